// Round 16
// baseline (212.240 us; speedup 1.0000x reference)
//
#include <hip/hip_runtime.h>
#include <math.h>

namespace {
constexpr int B = 2, S = 2048, D = 1024, H = 16, DH = 64;
constexpr int BH = B * H;               // 32
constexpr int BS = B * S;               // 4096
constexpr size_t MAT = (size_t)BS * D;  // 4194304 elems per (B,S,D) buffer
constexpr int QT = S / 64;              // 32 q-tiles
}

typedef __attribute__((ext_vector_type(8))) short s16x8;
typedef __attribute__((ext_vector_type(4))) short s16x4;
typedef __attribute__((ext_vector_type(4))) float f32x4;

__device__ inline unsigned short f2bf(float f) {
  union { float f; unsigned u; } c; c.f = f;
  unsigned r = c.u + 0x7fffu + ((c.u >> 16) & 1u);
  return (unsigned short)(r >> 16);
}
// fast round-half-up bf16 (fine for p >= 0)
__device__ inline short f2bft(float f) {
  union { float f; unsigned u; } c; c.f = f;
  return (short)((c.u + 0x8000u) >> 16);
}
__device__ inline float bf2f(short s) {
  union { unsigned u; float f; } c;
  c.u = ((unsigned)(unsigned short)s) << 16;
  return c.f;
}
// async global->LDS, 16 B per lane; LDS dest = wave-uniform base + lane*16.
// R9 lesson: lane->global mapping must be segment-identity; permuting lanes
// within the 128B segment defeats the DMA coalescer (61 -> 99 us).
__device__ inline void gld16(const unsigned short* g, unsigned short* l) {
  __builtin_amdgcn_global_load_lds(
      (const __attribute__((address_space(1))) unsigned int*)g,
      (__attribute__((address_space(3))) unsigned int*)l, 16, 0, 0);
}

// ---- Fused prep: convw (blocks 0..4095) | ln (4096..8191) | phase (8192..) ----
__global__ __launch_bounds__(256) void k_prep(
    const float* __restrict__ x, const float* __restrict__ gamma,
    const float* __restrict__ beta, unsigned short* __restrict__ h,
    const float* __restrict__ phase, const float* __restrict__ cp,
    const float* __restrict__ bal, float* __restrict__ Th,
    float* __restrict__ Lt, const float* __restrict__ W0,
    const float* __restrict__ W1, const float* __restrict__ W2,
    const float* __restrict__ W3, unsigned short* __restrict__ T0,
    unsigned short* __restrict__ T1, unsigned short* __restrict__ T2,
    unsigned short* __restrict__ T3) {
  __shared__ float shbuf[32 * 33];
  int id = blockIdx.x;
  int t = threadIdx.x;
  if (id < 4096) {
    // ---- weight transpose + bf16 convert: Wt[n][k] ----
    int z = id & 3;
    int bx = ((id >> 2) & 31) * 32;  // n base
    int by = (id >> 7) * 32;         // k base
    const float* W = (z == 0) ? W0 : (z == 1) ? W1 : (z == 2) ? W2 : W3;
    unsigned short* T = (z == 0) ? T0 : (z == 1) ? T1 : (z == 2) ? T2 : T3;
    int tc = t & 31, tr = t >> 5;
    float(*tile)[33] = (float(*)[33])shbuf;
#pragma unroll
    for (int i = 0; i < 4; i++)
      tile[tr + 8 * i][tc] = W[(size_t)(by + tr + 8 * i) * D + bx + tc];
    __syncthreads();
#pragma unroll
    for (int i = 0; i < 4; i++)
      T[(size_t)(bx + tr + 8 * i) * D + by + tc] = f2bf(tile[tc][tr + 8 * i]);
  } else if (id < 8192) {
    // ---- LayerNorm row, bf16 out ----
    int row = id - 4096;
    float* red = shbuf;
    const float* xr = x + (size_t)row * D;
    float v[4];
    float s = 0.f;
#pragma unroll
    for (int i = 0; i < 4; i++) {
      v[i] = xr[t + 256 * i];
      s += v[i];
    }
    red[t] = s;
    __syncthreads();
    for (int off = 128; off > 0; off >>= 1) {
      if (t < off) red[t] += red[t + off];
      __syncthreads();
    }
    float mu = red[0] * (1.0f / D);
    __syncthreads();
    float s2 = 0.f;
#pragma unroll
    for (int i = 0; i < 4; i++) {
      float d0 = v[i] - mu;
      s2 += d0 * d0;
    }
    red[t] = s2;
    __syncthreads();
    for (int off = 128; off > 0; off >>= 1) {
      if (t < off) red[t] += red[t + off];
      __syncthreads();
    }
    float r = rsqrtf(red[0] * (1.0f / D) + 1e-5f);
    unsigned short* hr = h + (size_t)row * D;
#pragma unroll
    for (int i = 0; i < 4; i++) {
      int c = t + 256 * i;
      hr[c] = f2bf((v[i] - mu) * r * gamma[c] + beta[c]);
    }
  } else {
    // ---- carrier resonance: Th and Lt = log2(T+1e-6)/tau ----
    int idx = (id - 8192) * 256 + t;  // over BH*S = 65536
    int s = idx & (S - 1);
    int bh = idx >> 11;
    int hh = bh & (H - 1);
    int b = bh >> 4;
    float tau = fminf(fmaxf(1.0f / (2.0f * bal[0] + 1e-8f), 0.1f), 10.0f);
    float c = cosf((phase[b * S + s] - cp[hh]) * 0.5f);
    float T = c * c;
    Th[idx] = T;
    Lt[idx] = __log2f(T + 1e-6f) * (1.0f / tau);
  }
}

// ---- R17: triple-buffered async GEMM k-loop, depth-2 prefetch, vmcnt(4) ----
// (kept for k_gemm_out_mfma; 4 waves, 4 loads/wave/step)
#define MFMA_GEMM_LOOP_TBUF(AP, BP)                                           \
  do {                                                                        \
    gld16(AP, &As[0][chunkA][0]);                                             \
    gld16(AP + (size_t)16 * D, &As[0][chunkA + 16][0]);                       \
    gld16(BP, &Bs[0][chunkA][0]);                                             \
    gld16(BP + (size_t)16 * D, &Bs[0][chunkA + 16][0]);                       \
    gld16(AP + 32, &As[1][chunkA][0]);                                        \
    gld16(AP + (size_t)16 * D + 32, &As[1][chunkA + 16][0]);                  \
    gld16(BP + 32, &Bs[1][chunkA][0]);                                        \
    gld16(BP + (size_t)16 * D + 32, &Bs[1][chunkA + 16][0]);                  \
    int cur = 0;                                                              \
    for (int k0 = 0; k0 < D; k0 += 32) {                                      \
      if (k0 + 32 < D)                                                        \
        asm volatile("s_waitcnt vmcnt(4)" ::: "memory");                      \
      else                                                                    \
        asm volatile("s_waitcnt vmcnt(0)" ::: "memory");                      \
      asm volatile("s_barrier" ::: "memory");                                 \
      if (k0 + 64 < D) {                                                      \
        int nxt = (cur >= 1) ? cur - 1 : 2; /* (cur+2)%3 */                   \
        gld16(AP + k0 + 64, &As[nxt][chunkA][0]);                             \
        gld16(AP + (size_t)16 * D + k0 + 64, &As[nxt][chunkA + 16][0]);       \
        gld16(BP + k0 + 64, &Bs[nxt][chunkA][0]);                             \
        gld16(BP + (size_t)16 * D + k0 + 64, &Bs[nxt][chunkA + 16][0]);       \
      }                                                                       \
      s16x8 af[4], bf[4];                                                     \
      _Pragma("unroll") for (int i = 0; i < 4; i++) {                         \
        af[i] = *(const s16x8*)&As[cur][wm + i * 16 + lane16][quad * 8];      \
        bf[i] = *(const s16x8*)&Bs[cur][wn + i * 16 + lane16][quad * 8];      \
      }                                                                       \
      _Pragma("unroll") for (int i = 0; i < 4; i++)                           \
          _Pragma("unroll") for (int j = 0; j < 4; j++) acc[i][j] =           \
          __builtin_amdgcn_mfma_f32_16x16x32_bf16(af[i], bf[j], acc[i][j],    \
                                                  0, 0, 0);                   \
      cur = (cur == 2) ? 0 : cur + 1;                                         \
    }                                                                         \
  } while (0)

// ------- Fused Q/K/V^T projection, R18: BM=256 x BN=128, 512 thr, 8 waves ---
// Measured R18: dropped out of top-5 (<50us, was 65us at 128^2).
__global__ __launch_bounds__(512) void k_gemm_qkvv(
    const unsigned short* __restrict__ hm, const unsigned short* __restrict__ Wq,
    const unsigned short* __restrict__ Wk, const unsigned short* __restrict__ Wv,
    const float* __restrict__ exps, unsigned short* __restrict__ q,
    unsigned short* __restrict__ kc, unsigned short* __restrict__ vt) {
  __shared__ __align__(16) unsigned short As[3][256][32];  // 48KB
  __shared__ __align__(16) unsigned short Bs[3][128][32];  // 24KB
  int id = blockIdx.x;
  int xcd = id & 7;
  int g = id >> 3;       // 0..47
  int z = g >> 4;        // 0=Q,1=K,2=V^T
  int w = g & 15;
  const unsigned short *Ap, *Bp;
  int tileM, tileN;
  if (z < 2) {
    Ap = hm; Bp = (z == 0) ? Wq : Wk;
    tileM = ((xcd >> 1) * 4 + (w >> 2)) * 256;  // seq: 16 tiles of 256
    tileN = ((xcd & 1) * 4 + (w & 3)) * 128;    // outdim: 8 tiles of 128
  } else {
    Ap = Wv; Bp = hm;
    tileM = ((xcd & 1) * 2 + (w >> 3)) * 256;   // outdim: 4 tiles of 256
    tileN = ((xcd >> 1) * 8 + (w & 7)) * 128;   // seq: 32 tiles of 128
  }
  int t = threadIdx.x;
  int wave = t >> 6, lane = t & 63, lane16 = lane & 15, quad = lane >> 4;
  int wm = (wave >> 1) * 64;   // 0..192 over BM=256
  int wn = (wave & 1) * 64;    // 0..64  over BN=128
  int chunkA = wave * 32;      // A rows this wave stages (2 gld16)
  int chunkB = wave * 16;      // B rows this wave stages (1 gld16)
  int srow = (lane >> 2), scol = (lane & 3) * 8;
  const unsigned short* aptr = Ap + (size_t)(tileM + chunkA + srow) * D + scol;
  const unsigned short* bptr = Bp + (size_t)(tileN + chunkB + srow) * D + scol;
  f32x4 acc[4][4] = {};
  // prologue: stage k-steps 0 and 1 (buffers 0,1); 6 loads in flight
  gld16(aptr, &As[0][chunkA][0]);
  gld16(aptr + (size_t)16 * D, &As[0][chunkA + 16][0]);
  gld16(bptr, &Bs[0][chunkB][0]);
  gld16(aptr + 32, &As[1][chunkA][0]);
  gld16(aptr + (size_t)16 * D + 32, &As[1][chunkA + 16][0]);
  gld16(bptr + 32, &Bs[1][chunkB][0]);
  int cur = 0;
  for (int k0 = 0; k0 < D; k0 += 32) {
    if (k0 + 32 < D)
      asm volatile("s_waitcnt vmcnt(3)" ::: "memory");
    else
      asm volatile("s_waitcnt vmcnt(0)" ::: "memory");
    asm volatile("s_barrier" ::: "memory");
    if (k0 + 64 < D) {
      int nxt = (cur >= 1) ? cur - 1 : 2;  // (cur+2)%3
      gld16(aptr + k0 + 64, &As[nxt][chunkA][0]);
      gld16(aptr + (size_t)16 * D + k0 + 64, &As[nxt][chunkA + 16][0]);
      gld16(bptr + k0 + 64, &Bs[nxt][chunkB][0]);
    }
    s16x8 af[4], bf[4];
#pragma unroll
    for (int i = 0; i < 4; i++) {
      af[i] = *(const s16x8*)&As[cur][wm + i * 16 + lane16][quad * 8];
      bf[i] = *(const s16x8*)&Bs[cur][wn + i * 16 + lane16][quad * 8];
    }
#pragma unroll
    for (int i = 0; i < 4; i++)
#pragma unroll
      for (int j = 0; j < 4; j++)
        acc[i][j] = __builtin_amdgcn_mfma_f32_16x16x32_bf16(af[i], bf[j],
                                                            acc[i][j], 0, 0, 0);
    cur = (cur == 2) ? 0 : cur + 1;
  }
  if (z < 2) {
    unsigned short* __restrict__ outp = (z == 0) ? q : kc;
    float e0 = exps[tileN >> 6];
    float e1 = exps[(tileN >> 6) + 1];
#pragma unroll
    for (int i = 0; i < 4; i++) {
#pragma unroll
      for (int r = 0; r < 4; r++) {
        int row = tileM + wm + i * 16 + quad * 4 + r;
        int b = row >> 11, s = row & (S - 1);
#pragma unroll
        for (int j = 0; j < 4; j++) {
          int cloc = wn + j * 16 + lane16;  // 0..127
          int head = (tileN + cloc) >> 6;
          int dh = cloc & 63;
          float val = acc[i][j][r];
          if (z != 0) {
            float e = (cloc >> 6) ? e1 : e0;
            float sgn = (val > 0.f) ? 1.f : ((val < 0.f) ? -1.f : 0.f);
            float mg = fmaxf(fabsf(val), 1e-8f);
            val = sgn * exp2f(e * __log2f(mg));
          }
          outp[((size_t)(b * H + head) * S + s) * DH + dh] = f2bf(val);
        }
      }
    }
  } else {
#pragma unroll
    for (int i = 0; i < 4; i++) {
#pragma unroll
      for (int r = 0; r < 4; r++) {
        int m = tileM + wm + i * 16 + quad * 4 + r;  // outdim
        int head = m >> 6, dh = m & 63;
        float e = exps[head];
#pragma unroll
        for (int j = 0; j < 4; j++) {
          int n = tileN + wn + j * 16 + lane16;  // seq
          int b = n >> 11, s = n & (S - 1);
          float val = acc[i][j][r];
          float sgn = (val > 0.f) ? 1.f : ((val < 0.f) ? -1.f : 0.f);
          float mg = fmaxf(fabsf(val), 1e-8f);
          val = sgn * exp2f(e * __log2f(mg));
          vt[((size_t)(b * H + head) * DH + dh) * S + s] = f2bf(val);
        }
      }
    }
  }
}

// ------ Output projection MFMA GEMM + residual, flat grid 256 ------
// Same XCD-aware decode: each XCD reads a 2MB ao-slice + 1MB wo-slice.
__global__ __launch_bounds__(256) void k_gemm_out_mfma(
    const unsigned short* __restrict__ am, const unsigned short* __restrict__ Wt,
    const float* __restrict__ x, float* __restrict__ outp) {
  __shared__ __align__(16) unsigned short As[3][128][32];
  __shared__ __align__(16) unsigned short Bs[3][128][32];
  int id = blockIdx.x;
  int xcd = id & 7;
  int inner = id >> 3;  // 0..31
  int tileM = ((xcd >> 1) * 8 + (inner >> 2)) * 128;
  int tileN = ((xcd & 1) * 4 + (inner & 3)) * 128;
  int t = threadIdx.x;
  int wave = t >> 6, lane = t & 63, lane16 = lane & 15, quad = lane >> 4;
  int wm = (wave >> 1) * 64, wn = (wave & 1) * 64;
  int chunkA = wave * 32;
  int srow = (lane >> 2), scol = (lane & 3) * 8;
  const unsigned short* aptr = am + (size_t)(tileM + chunkA + srow) * D + scol;
  const unsigned short* bptr = Wt + (size_t)(tileN + chunkA + srow) * D + scol;
  f32x4 acc[4][4] = {};
  MFMA_GEMM_LOOP_TBUF(aptr, bptr);
#pragma unroll
  for (int i = 0; i < 4; i++) {
#pragma unroll
    for (int r = 0; r < 4; r++) {
      int row = tileM + wm + i * 16 + quad * 4 + r;
      const float* xr = x + (size_t)row * D;
      float* orow = outp + (size_t)row * D;
#pragma unroll
      for (int j = 0; j < 4; j++) {
        int col = tileN + wn + j * 16 + lane16;
        orow[col] = xr[col] + acc[i][j][r];
      }
    }
  }
}

// ------- MFMA flash attention R25: R24 (swizzle WIN) + att[2] PV pipeline --
// R24 measured: conflicts 5.95M->1.62M, 50.0->47.0us (prediction matched).
// Remaining: VALUBusy 56% top pipe; per-tile serial chain QK->SM->Pt->PV.
// T15 mechanism: keep two P-tiles live; PV(kt-1) (pure MFMA, inputs ready)
// overlaps QK+SM(kt) (VALU) -> PV + Pt read latency leave the chain.
// Pt[2] (+9KB); Vs[3] (PV(kt-1) must survive stage of kt+1: (kt+1)-(kt-1)
// = 2 mod 3 -> rotation hazard-free); Ks[2]. LDS 59.9KB -> 2 blocks/CU
// (the measured operating point). Also: QK C-in seeded with lt (saves 16
// v_add/lane/tile). Swizzle from R24 unchanged.
__global__ __launch_bounds__(256) void k_attn_mfma(
    const unsigned short* __restrict__ q, const unsigned short* __restrict__ kc,
    const unsigned short* __restrict__ vt, const float* __restrict__ Th,
    const float* __restrict__ Lt, const float* __restrict__ bal,
    unsigned short* __restrict__ ao) {
  __shared__ __align__(16) unsigned short Ks[2][64][64];   // [buf][key][dh] swz
  __shared__ __align__(16) unsigned short Vs[3][64][64];   // [buf][dh][key] swz
  __shared__ __align__(16) unsigned short Pt[2][4][16][72];// [pbuf][wave][q][k]
  __shared__ __align__(16) float Lts[2][64];
  int id = blockIdx.x;
  int bh = (id & 7) + 8 * ((id >> 3) & 3);  // XCD-affine head mapping
  int qt = QT - 1 - (id >> 5);              // 31..0: long blocks first
  int t = threadIdx.x;
  int wave = t >> 6, lane = t & 63;
  int lane16 = lane & 15, quad = lane >> 4;
  float tau = fminf(fmaxf(1.0f / (2.0f * bal[0] + 1e-8f), 0.1f), 10.0f);
  float c1 = 0.125f * (1.0f / tau) * 1.44269504f;  // fold into Q
  const unsigned short* qb = q + (size_t)bh * S * DH;
  const unsigned short* kb = kc + (size_t)bh * S * DH;
  const unsigned short* vb = vt + (size_t)bh * DH * S;
  const float* Ltb = Lt + (size_t)bh * S;
  int b = bh >> 4, hh = bh & (H - 1);
  int cr = t >> 3, cc = (t & 7) * 8;  // staging coords
  int wsw = ((cr & 7) << 4);          // write-side swizzle (same for cr+32)
  int wcol = (cc * 2) ^ wsw;          // swizzled byte offset within row
  s16x8 nk0, nk1, nv0, nv1;
  float4 nlt;
#define STAGE_LOAD(KT)                                                  \
  do {                                                                  \
    nk0 = *(const s16x8*)(kb + (size_t)((KT) * 64 + cr) * DH + cc);     \
    nk1 = *(const s16x8*)(kb + (size_t)((KT) * 64 + cr + 32) * DH + cc);\
    nv0 = *(const s16x8*)(vb + (size_t)cr * S + (KT) * 64 + cc);        \
    nv1 = *(const s16x8*)(vb + (size_t)(cr + 32) * S + (KT) * 64 + cc); \
    if (t < 16) nlt = ((const float4*)(Ltb + (KT) * 64))[t];            \
  } while (0)
#define STAGE_WRITE(KT_)                                                \
  do {                                                                  \
    int kb_ = (KT_) & 1, vb_ = (KT_) % 3;                               \
    *(s16x8*)((char*)&Ks[kb_][cr][0] + wcol) = nk0;                     \
    *(s16x8*)((char*)&Ks[kb_][cr + 32][0] + wcol) = nk1;                \
    *(s16x8*)((char*)&Vs[vb_][cr][0] + wcol) = nv0;                     \
    *(s16x8*)((char*)&Vs[vb_][cr + 32][0] + wcol) = nv1;                \
    if (t < 16) ((float4*)Lts[kb_])[t] = nlt;                           \
  } while (0)
  int qbase = qt * 64 + wave * 16;
  // Q as B-frag (B[k=quad*8+j][n=lane16]), pre-scaled by c1 in bf16
  s16x8 qa0, qa1;
  {
    s16x8 r0 = *(const s16x8*)(qb + (size_t)(qbase + lane16) * DH + quad * 8);
    s16x8 r1 =
        *(const s16x8*)(qb + (size_t)(qbase + lane16) * DH + 32 + quad * 8);
#pragma unroll
    for (int i = 0; i < 8; i++) {
      qa0[i] = f2bft(bf2f(r0[i]) * c1);
      qa1[i] = f2bft(bf2f(r1[i]) * c1);
    }
  }
  f32x4 O[4] = {};
  float lacc = 0.f;
  int rsw = ((lane16 & 7) << 4);      // read-side swizzle (rows = *16+lane16)
  int rc0 = (quad * 16) ^ rsw;        // swizzled byte col for first half
  int rc1 = (64 + quad * 16) ^ rsw;   // second half (dh 32..63 / keys 32..63)
  // QK^T + softmax for tile KT: seeds MFMA C with lt, writes Pt[KT&1]
#define QKSM(KT)                                                        \
  do {                                                                  \
    int kbuf_ = (KT) & 1;                                               \
    bool diag_ = ((KT) == qt);                                          \
    _Pragma("unroll") for (int jk = 0; jk < 4; jk++) {                  \
      s16x8 ka0 = *(const s16x8*)((const char*)&Ks[kbuf_][jk * 16 +     \
                                  lane16][0] + rc0);                    \
      s16x8 ka1 = *(const s16x8*)((const char*)&Ks[kbuf_][jk * 16 +     \
                                  lane16][0] + rc1);                    \
      float4 ltv = *(const float4*)&Lts[kbuf_][jk * 16 + quad * 4];     \
      f32x4 st = {ltv.x, ltv.y, ltv.z, ltv.w};                          \
      st = __builtin_amdgcn_mfma_f32_16x16x32_bf16(ka0, qa0, st, 0, 0, 0); \
      st = __builtin_amdgcn_mfma_f32_16x16x32_bf16(ka1, qa1, st, 0, 0, 0); \
      s16x4 pk;                                                         \
      _Pragma("unroll") for (int r = 0; r < 4; r++) {                   \
        float p = exp2f(fminf(st[r], 126.f));                           \
        if (diag_)                                                      \
          p = (jk * 16 + quad * 4 + r <= wave * 16 + lane16) ? p : 0.f; \
        lacc += p;                                                      \
        pk[r] = f2bft(p);                                               \
      }                                                                 \
      *(s16x4*)&Pt[kbuf_][wave][lane16][jk * 16 + quad * 4] = pk;       \
    }                                                                   \
  } while (0)
  // PV for tile KT: O += V^T(KT) * P(KT); pure MFMA, inputs ready
#define PVSTEP(KT)                                                      \
  do {                                                                  \
    int pb_ = (KT) & 1, vbuf_ = (KT) % 3;                               \
    s16x8 pf0 = *(const s16x8*)&Pt[pb_][wave][lane16][quad * 8];        \
    s16x8 pf1 = *(const s16x8*)&Pt[pb_][wave][lane16][32 + quad * 8];   \
    _Pragma("unroll") for (int d = 0; d < 4; d++) {                     \
      s16x8 av0 = *(const s16x8*)((const char*)&Vs[vbuf_][d * 16 +      \
                                  lane16][0] + rc0);                    \
      s16x8 av1 = *(const s16x8*)((const char*)&Vs[vbuf_][d * 16 +      \
                                  lane16][0] + rc1);                    \
      O[d] = __builtin_amdgcn_mfma_f32_16x16x32_bf16(av0, pf0, O[d], 0, 0, 0); \
      O[d] = __builtin_amdgcn_mfma_f32_16x16x32_bf16(av1, pf1, O[d], 0, 0, 0); \
    }                                                                   \
  } while (0)
  // prologue: stage tile 0, compute QK+SM(0) with tile-1 stage overlapped
  STAGE_LOAD(0);
  STAGE_WRITE(0);
  __syncthreads();
  if (qt >= 1) STAGE_LOAD(1);
  QKSM(0);
  if (qt >= 1) STAGE_WRITE(1);
  __syncthreads();
  // steady state: PV(kt-1) [MFMA] overlaps QK+SM(kt) [MFMA+VALU]
  for (int kt = 1; kt <= qt; kt++) {
    if (kt < qt) STAGE_LOAD(kt + 1);
    PVSTEP(kt - 1);
    QKSM(kt);
    if (kt < qt) STAGE_WRITE(kt + 1);
    __syncthreads();
  }
  PVSTEP(qt);
  // reduce l across the 4 quads (each quad summed a disjoint key subset)
  lacc += __shfl_xor(lacc, 16, 64);
  lacc += __shfl_xor(lacc, 32, 64);
  int qg = qbase + lane16;
  float scl = Th[(size_t)bh * S + qg] / lacc;
  unsigned short* op = ao + (size_t)(b * S + qg) * D + hh * DH;
#pragma unroll
  for (int d = 0; d < 4; d++) {
    s16x4 pk;
#pragma unroll
    for (int r = 0; r < 4; r++) pk[r] = f2bft(O[d][r] * scl);
    *(s16x4*)(op + d * 16 + quad * 4) = pk;
  }
#undef STAGE_LOAD
#undef STAGE_WRITE
#undef QKSM
#undef PVSTEP
}

extern "C" void kernel_launch(void* const* d_in, const int* in_sizes, int n_in,
                              void* d_out, int out_size, void* d_ws,
                              size_t ws_size, hipStream_t stream) {
  const float* x = (const float*)d_in[0];
  const float* phase = (const float*)d_in[1];
  const float* Wq = (const float*)d_in[2];
  const float* Wk = (const float*)d_in[3];
  const float* Wv = (const float*)d_in[4];
  const float* Wo = (const float*)d_in[5];
  const float* gamma = (const float*)d_in[6];
  const float* beta = (const float*)d_in[7];
  const float* exps = (const float*)d_in[8];
  const float* cph = (const float*)d_in[9];
  const float* bal = (const float*)d_in[10];
  float* out = (float*)d_out;

  unsigned short* hbuf = (unsigned short*)d_ws;        // MAT bf16
  float* Thbuf = (float*)(hbuf + MAT);                 // BH*S fp32
  float* Ltbuf = Thbuf + (size_t)BH * S;               // BH*S fp32
  unsigned short* qbuf = (unsigned short*)(Ltbuf + (size_t)BH * S);
  unsigned short* kbuf = qbuf + MAT;
  unsigned short* vtbuf = kbuf + MAT;                  // V^T bf16 (B,H,DH,S)
  unsigned short* aobuf = vtbuf + MAT;                 // attn out bf16 (B,S,D)
  unsigned short* wq_t = aobuf + MAT;                  // 4 x D*D bf16
  unsigned short* wk_t = wq_t + (size_t)D * D;
  unsigned short* wv_t = wk_t + (size_t)D * D;
  unsigned short* wo_t = wv_t + (size_t)D * D;

  hipLaunchKernelGGL(k_prep, dim3(8448), dim3(256), 0, stream, x, gamma, beta,
                     hbuf, phase, cph, bal, Thbuf, Ltbuf, Wq, Wk, Wv, Wo, wq_t,
                     wk_t, wv_t, wo_t);
  hipLaunchKernelGGL(k_gemm_qkvv, dim3(384), dim3(512), 0, stream, hbuf, wq_t,
                     wk_t, wv_t, exps, qbuf, kbuf, vtbuf);
  hipLaunchKernelGGL(k_attn_mfma, dim3(1024), dim3(256), 0, stream, qbuf,
                     kbuf, vtbuf, Thbuf, Ltbuf, bal, aobuf);
  hipLaunchKernelGGL(k_gemm_out_mfma, dim3(256), dim3(256), 0, stream, aobuf,
                     wo_t, x, out);
}

// Round 18
// 199.180 us; speedup vs baseline: 1.0656x; 1.0656x over previous
//
#include <hip/hip_runtime.h>
#include <math.h>

namespace {
constexpr int B = 2, S = 2048, D = 1024, H = 16, DH = 64;
constexpr int BH = B * H;               // 32
constexpr int BS = B * S;               // 4096
constexpr size_t MAT = (size_t)BS * D;  // 4194304 elems per (B,S,D) buffer
constexpr int QT = S / 64;              // 32 q-tiles
}

typedef __attribute__((ext_vector_type(8))) short s16x8;
typedef __attribute__((ext_vector_type(4))) short s16x4;
typedef __attribute__((ext_vector_type(4))) float f32x4;

__device__ inline unsigned short f2bf(float f) {
  union { float f; unsigned u; } c; c.f = f;
  unsigned r = c.u + 0x7fffu + ((c.u >> 16) & 1u);
  return (unsigned short)(r >> 16);
}
// fast round-half-up bf16 (fine for p >= 0)
__device__ inline short f2bft(float f) {
  union { float f; unsigned u; } c; c.f = f;
  return (short)((c.u + 0x8000u) >> 16);
}
__device__ inline float bf2f(short s) {
  union { unsigned u; float f; } c;
  c.u = ((unsigned)(unsigned short)s) << 16;
  return c.f;
}
// async global->LDS, 16 B per lane; LDS dest = wave-uniform base + lane*16.
// R9 lesson: lane->global mapping must be segment-identity; permuting lanes
// within the 128B segment defeats the DMA coalescer (61 -> 99 us).
__device__ inline void gld16(const unsigned short* g, unsigned short* l) {
  __builtin_amdgcn_global_load_lds(
      (const __attribute__((address_space(1))) unsigned int*)g,
      (__attribute__((address_space(3))) unsigned int*)l, 16, 0, 0);
}

// ---- Fused prep: convw (blocks 0..4095) | ln (4096..8191) | phase (8192..) ----
__global__ __launch_bounds__(256) void k_prep(
    const float* __restrict__ x, const float* __restrict__ gamma,
    const float* __restrict__ beta, unsigned short* __restrict__ h,
    const float* __restrict__ phase, const float* __restrict__ cp,
    const float* __restrict__ bal, float* __restrict__ Th,
    float* __restrict__ Lt, const float* __restrict__ W0,
    const float* __restrict__ W1, const float* __restrict__ W2,
    const float* __restrict__ W3, unsigned short* __restrict__ T0,
    unsigned short* __restrict__ T1, unsigned short* __restrict__ T2,
    unsigned short* __restrict__ T3) {
  __shared__ float shbuf[32 * 33];
  int id = blockIdx.x;
  int t = threadIdx.x;
  if (id < 4096) {
    // ---- weight transpose + bf16 convert: Wt[n][k] ----
    int z = id & 3;
    int bx = ((id >> 2) & 31) * 32;  // n base
    int by = (id >> 7) * 32;         // k base
    const float* W = (z == 0) ? W0 : (z == 1) ? W1 : (z == 2) ? W2 : W3;
    unsigned short* T = (z == 0) ? T0 : (z == 1) ? T1 : (z == 2) ? T2 : T3;
    int tc = t & 31, tr = t >> 5;
    float(*tile)[33] = (float(*)[33])shbuf;
#pragma unroll
    for (int i = 0; i < 4; i++)
      tile[tr + 8 * i][tc] = W[(size_t)(by + tr + 8 * i) * D + bx + tc];
    __syncthreads();
#pragma unroll
    for (int i = 0; i < 4; i++)
      T[(size_t)(bx + tr + 8 * i) * D + by + tc] = f2bf(tile[tc][tr + 8 * i]);
  } else if (id < 8192) {
    // ---- LayerNorm row, bf16 out ----
    int row = id - 4096;
    float* red = shbuf;
    const float* xr = x + (size_t)row * D;
    float v[4];
    float s = 0.f;
#pragma unroll
    for (int i = 0; i < 4; i++) {
      v[i] = xr[t + 256 * i];
      s += v[i];
    }
    red[t] = s;
    __syncthreads();
    for (int off = 128; off > 0; off >>= 1) {
      if (t < off) red[t] += red[t + off];
      __syncthreads();
    }
    float mu = red[0] * (1.0f / D);
    __syncthreads();
    float s2 = 0.f;
#pragma unroll
    for (int i = 0; i < 4; i++) {
      float d0 = v[i] - mu;
      s2 += d0 * d0;
    }
    red[t] = s2;
    __syncthreads();
    for (int off = 128; off > 0; off >>= 1) {
      if (t < off) red[t] += red[t + off];
      __syncthreads();
    }
    float r = rsqrtf(red[0] * (1.0f / D) + 1e-5f);
    unsigned short* hr = h + (size_t)row * D;
#pragma unroll
    for (int i = 0; i < 4; i++) {
      int c = t + 256 * i;
      hr[c] = f2bf((v[i] - mu) * r * gamma[c] + beta[c]);
    }
  } else {
    // ---- carrier resonance: Th and Lt = log2(T+1e-6)/tau ----
    int idx = (id - 8192) * 256 + t;  // over BH*S = 65536
    int s = idx & (S - 1);
    int bh = idx >> 11;
    int hh = bh & (H - 1);
    int b = bh >> 4;
    float tau = fminf(fmaxf(1.0f / (2.0f * bal[0] + 1e-8f), 0.1f), 10.0f);
    float c = cosf((phase[b * S + s] - cp[hh]) * 0.5f);
    float T = c * c;
    Th[idx] = T;
    Lt[idx] = __log2f(T + 1e-6f) * (1.0f / tau);
  }
}

// ------- Fused Q/K/V^T projection, R18: BM=256 x BN=128, 512 thr, 8 waves ---
// Measured R18: dropped out of top-5 (<50us, was 65us at 128^2).
__global__ __launch_bounds__(512) void k_gemm_qkvv(
    const unsigned short* __restrict__ hm, const unsigned short* __restrict__ Wq,
    const unsigned short* __restrict__ Wk, const unsigned short* __restrict__ Wv,
    const float* __restrict__ exps, unsigned short* __restrict__ q,
    unsigned short* __restrict__ kc, unsigned short* __restrict__ vt) {
  __shared__ __align__(16) unsigned short As[3][256][32];  // 48KB
  __shared__ __align__(16) unsigned short Bs[3][128][32];  // 24KB
  int id = blockIdx.x;
  int xcd = id & 7;
  int g = id >> 3;       // 0..47
  int z = g >> 4;        // 0=Q,1=K,2=V^T
  int w = g & 15;
  const unsigned short *Ap, *Bp;
  int tileM, tileN;
  if (z < 2) {
    Ap = hm; Bp = (z == 0) ? Wq : Wk;
    tileM = ((xcd >> 1) * 4 + (w >> 2)) * 256;  // seq: 16 tiles of 256
    tileN = ((xcd & 1) * 4 + (w & 3)) * 128;    // outdim: 8 tiles of 128
  } else {
    Ap = Wv; Bp = hm;
    tileM = ((xcd & 1) * 2 + (w >> 3)) * 256;   // outdim: 4 tiles of 256
    tileN = ((xcd >> 1) * 8 + (w & 7)) * 128;   // seq: 32 tiles of 128
  }
  int t = threadIdx.x;
  int wave = t >> 6, lane = t & 63, lane16 = lane & 15, quad = lane >> 4;
  int wm = (wave >> 1) * 64;   // 0..192 over BM=256
  int wn = (wave & 1) * 64;    // 0..64  over BN=128
  int chunkA = wave * 32;      // A rows this wave stages (2 gld16)
  int chunkB = wave * 16;      // B rows this wave stages (1 gld16)
  int srow = (lane >> 2), scol = (lane & 3) * 8;
  const unsigned short* aptr = Ap + (size_t)(tileM + chunkA + srow) * D + scol;
  const unsigned short* bptr = Bp + (size_t)(tileN + chunkB + srow) * D + scol;
  f32x4 acc[4][4] = {};
  // prologue: stage k-steps 0 and 1 (buffers 0,1); 6 loads in flight
  gld16(aptr, &As[0][chunkA][0]);
  gld16(aptr + (size_t)16 * D, &As[0][chunkA + 16][0]);
  gld16(bptr, &Bs[0][chunkB][0]);
  gld16(aptr + 32, &As[1][chunkA][0]);
  gld16(aptr + (size_t)16 * D + 32, &As[1][chunkA + 16][0]);
  gld16(bptr + 32, &Bs[1][chunkB][0]);
  int cur = 0;
  for (int k0 = 0; k0 < D; k0 += 32) {
    if (k0 + 32 < D)
      asm volatile("s_waitcnt vmcnt(3)" ::: "memory");
    else
      asm volatile("s_waitcnt vmcnt(0)" ::: "memory");
    asm volatile("s_barrier" ::: "memory");
    if (k0 + 64 < D) {
      int nxt = (cur >= 1) ? cur - 1 : 2;  // (cur+2)%3
      gld16(aptr + k0 + 64, &As[nxt][chunkA][0]);
      gld16(aptr + (size_t)16 * D + k0 + 64, &As[nxt][chunkA + 16][0]);
      gld16(bptr + k0 + 64, &Bs[nxt][chunkB][0]);
    }
    s16x8 af[4], bf[4];
#pragma unroll
    for (int i = 0; i < 4; i++) {
      af[i] = *(const s16x8*)&As[cur][wm + i * 16 + lane16][quad * 8];
      bf[i] = *(const s16x8*)&Bs[cur][wn + i * 16 + lane16][quad * 8];
    }
#pragma unroll
    for (int i = 0; i < 4; i++)
#pragma unroll
      for (int j = 0; j < 4; j++)
        acc[i][j] = __builtin_amdgcn_mfma_f32_16x16x32_bf16(af[i], bf[j],
                                                            acc[i][j], 0, 0, 0);
    cur = (cur == 2) ? 0 : cur + 1;
  }
  if (z < 2) {
    unsigned short* __restrict__ outp = (z == 0) ? q : kc;
    float e0 = exps[tileN >> 6];
    float e1 = exps[(tileN >> 6) + 1];
#pragma unroll
    for (int i = 0; i < 4; i++) {
#pragma unroll
      for (int r = 0; r < 4; r++) {
        int row = tileM + wm + i * 16 + quad * 4 + r;
        int b = row >> 11, s = row & (S - 1);
#pragma unroll
        for (int j = 0; j < 4; j++) {
          int cloc = wn + j * 16 + lane16;  // 0..127
          int head = (tileN + cloc) >> 6;
          int dh = cloc & 63;
          float val = acc[i][j][r];
          if (z != 0) {
            float e = (cloc >> 6) ? e1 : e0;
            float sgn = (val > 0.f) ? 1.f : ((val < 0.f) ? -1.f : 0.f);
            float mg = fmaxf(fabsf(val), 1e-8f);
            val = sgn * exp2f(e * __log2f(mg));
          }
          outp[((size_t)(b * H + head) * S + s) * DH + dh] = f2bf(val);
        }
      }
    }
  } else {
#pragma unroll
    for (int i = 0; i < 4; i++) {
#pragma unroll
      for (int r = 0; r < 4; r++) {
        int m = tileM + wm + i * 16 + quad * 4 + r;  // outdim
        int head = m >> 6, dh = m & 63;
        float e = exps[head];
#pragma unroll
        for (int j = 0; j < 4; j++) {
          int n = tileN + wn + j * 16 + lane16;  // seq
          int b = n >> 11, s = n & (S - 1);
          float val = acc[i][j][r];
          float sgn = (val > 0.f) ? 1.f : ((val < 0.f) ? -1.f : 0.f);
          float mg = fmaxf(fabsf(val), 1e-8f);
          val = sgn * exp2f(e * __log2f(mg));
          vt[((size_t)(b * H + head) * DH + dh) * S + s] = f2bf(val);
        }
      }
    }
  }
}

// ------ Output projection R26: 128x64 tiles, grid 512 = 2 blocks/CU ------
// Theory: old grid 256 = 1 block/CU -> zero co-residency, all 32 per-step
// vmcnt+barrier drains exposed (R13 lesson: qkv needed >=2/CU to hide).
// Ledger shows ~152us non-attn time; this kernel is the prime suspect
// (~35-45us est). BN 128->64: Bs halves (36KB total, cap 4/CU), 3 gld16
// per wave per step (vmcnt(3) depth-2, mirrors verified R18 staging).
__global__ __launch_bounds__(256) void k_gemm_out_mfma(
    const unsigned short* __restrict__ am, const unsigned short* __restrict__ Wt,
    const float* __restrict__ x, float* __restrict__ outp) {
  __shared__ __align__(16) unsigned short As[3][128][32];  // 24KB
  __shared__ __align__(16) unsigned short Bs[3][64][32];   // 12KB
  int id = blockIdx.x;          // 0..511
  int xcd = id & 7;
  int inner = id >> 3;          // 0..63
  int tileM = ((xcd >> 1) * 8 + (inner >> 3)) * 128;  // 32 M-tiles
  int tileN = ((xcd & 1) * 8 + (inner & 7)) * 64;     // 16 N-tiles
  int t = threadIdx.x;
  int wave = t >> 6, lane = t & 63, lane16 = lane & 15, quad = lane >> 4;
  int wm = (wave >> 1) * 64;    // 0 or 64 over BM=128
  int wn = (wave & 1) * 32;     // 0 or 32 over BN=64
  int chunkA = wave * 32;       // A rows staged (2 gld16)
  int chunkB = wave * 16;       // B rows staged (1 gld16)
  int srow = (lane >> 2), scol = (lane & 3) * 8;
  const unsigned short* aptr = am + (size_t)(tileM + chunkA + srow) * D + scol;
  const unsigned short* bptr = Wt + (size_t)(tileN + chunkB + srow) * D + scol;
  f32x4 acc[4][2] = {};
  gld16(aptr, &As[0][chunkA][0]);
  gld16(aptr + (size_t)16 * D, &As[0][chunkA + 16][0]);
  gld16(bptr, &Bs[0][chunkB][0]);
  gld16(aptr + 32, &As[1][chunkA][0]);
  gld16(aptr + (size_t)16 * D + 32, &As[1][chunkA + 16][0]);
  gld16(bptr + 32, &Bs[1][chunkB][0]);
  int cur = 0;
  for (int k0 = 0; k0 < D; k0 += 32) {
    if (k0 + 32 < D)
      asm volatile("s_waitcnt vmcnt(3)" ::: "memory");
    else
      asm volatile("s_waitcnt vmcnt(0)" ::: "memory");
    asm volatile("s_barrier" ::: "memory");
    if (k0 + 64 < D) {
      int nxt = (cur >= 1) ? cur - 1 : 2;  // (cur+2)%3
      gld16(aptr + k0 + 64, &As[nxt][chunkA][0]);
      gld16(aptr + (size_t)16 * D + k0 + 64, &As[nxt][chunkA + 16][0]);
      gld16(bptr + k0 + 64, &Bs[nxt][chunkB][0]);
    }
    s16x8 af[4], bf[2];
#pragma unroll
    for (int i = 0; i < 4; i++)
      af[i] = *(const s16x8*)&As[cur][wm + i * 16 + lane16][quad * 8];
#pragma unroll
    for (int j = 0; j < 2; j++)
      bf[j] = *(const s16x8*)&Bs[cur][wn + j * 16 + lane16][quad * 8];
#pragma unroll
    for (int i = 0; i < 4; i++)
#pragma unroll
      for (int j = 0; j < 2; j++)
        acc[i][j] = __builtin_amdgcn_mfma_f32_16x16x32_bf16(af[i], bf[j],
                                                            acc[i][j], 0, 0, 0);
    cur = (cur == 2) ? 0 : cur + 1;
  }
#pragma unroll
  for (int i = 0; i < 4; i++) {
#pragma unroll
    for (int r = 0; r < 4; r++) {
      int row = tileM + wm + i * 16 + quad * 4 + r;
      const float* xr = x + (size_t)row * D;
      float* orow = outp + (size_t)row * D;
#pragma unroll
      for (int j = 0; j < 2; j++) {
        int col = tileN + wn + j * 16 + lane16;
        orow[col] = xr[col] + acc[i][j][r];
      }
    }
  }
}

// ------- MFMA flash attention R24 (verified 47.0us): swizzled Ks/Vs -------
// R25 post-mortem: att[2] pipeline regressed (58.3us, occ 18% = lost
// co-residency at 60KB LDS) -> reverted to R24 exactly. R24 measured:
// conflicts 5.95M->1.62M, 50.0->47.0us, LDS 42.5KB.
__global__ __launch_bounds__(256) void k_attn_mfma(
    const unsigned short* __restrict__ q, const unsigned short* __restrict__ kc,
    const unsigned short* __restrict__ vt, const float* __restrict__ Th,
    const float* __restrict__ Lt, const float* __restrict__ bal,
    unsigned short* __restrict__ ao) {
  __shared__ __align__(16) unsigned short Ks[2][64][64];   // [buf][key][dh] swz
  __shared__ __align__(16) unsigned short Vs[2][64][64];   // [buf][dh][key] swz
  __shared__ __align__(16) unsigned short Pt[4][16][72];   // [wave][query][key]
  __shared__ __align__(16) float Lts[2][64];
  int id = blockIdx.x;
  int bh = (id & 7) + 8 * ((id >> 3) & 3);  // XCD-affine head mapping
  int qt = QT - 1 - (id >> 5);              // 31..0: long blocks first
  int t = threadIdx.x;
  int wave = t >> 6, lane = t & 63;
  int lane16 = lane & 15, quad = lane >> 4;
  float tau = fminf(fmaxf(1.0f / (2.0f * bal[0] + 1e-8f), 0.1f), 10.0f);
  float c1 = 0.125f * (1.0f / tau) * 1.44269504f;  // fold into Q
  const unsigned short* qb = q + (size_t)bh * S * DH;
  const unsigned short* kb = kc + (size_t)bh * S * DH;
  const unsigned short* vb = vt + (size_t)bh * DH * S;
  const float* Ltb = Lt + (size_t)bh * S;
  int b = bh >> 4, hh = bh & (H - 1);
  int cr = t >> 3, cc = (t & 7) * 8;  // staging coords
  int wsw = ((cr & 7) << 4);          // write-side swizzle (same for cr+32)
  int wcol = (cc * 2) ^ wsw;          // swizzled byte offset within row
  s16x8 nk0, nk1, nv0, nv1;
  float4 nlt;
#define STAGE_LOAD(KT)                                                  \
  do {                                                                  \
    nk0 = *(const s16x8*)(kb + (size_t)((KT) * 64 + cr) * DH + cc);     \
    nk1 = *(const s16x8*)(kb + (size_t)((KT) * 64 + cr + 32) * DH + cc);\
    nv0 = *(const s16x8*)(vb + (size_t)cr * S + (KT) * 64 + cc);        \
    nv1 = *(const s16x8*)(vb + (size_t)(cr + 32) * S + (KT) * 64 + cc); \
    if (t < 16) nlt = ((const float4*)(Ltb + (KT) * 64))[t];            \
  } while (0)
#define STAGE_WRITE(BF)                                                 \
  do {                                                                  \
    *(s16x8*)((char*)&Ks[BF][cr][0] + wcol) = nk0;                      \
    *(s16x8*)((char*)&Ks[BF][cr + 32][0] + wcol) = nk1;                 \
    *(s16x8*)((char*)&Vs[BF][cr][0] + wcol) = nv0;                      \
    *(s16x8*)((char*)&Vs[BF][cr + 32][0] + wcol) = nv1;                 \
    if (t < 16) ((float4*)Lts[BF])[t] = nlt;                            \
  } while (0)
  int qbase = qt * 64 + wave * 16;
  // Q as B-frag (B[k=quad*8+j][n=lane16]), pre-scaled by c1 in bf16
  s16x8 qa0, qa1;
  {
    s16x8 r0 = *(const s16x8*)(qb + (size_t)(qbase + lane16) * DH + quad * 8);
    s16x8 r1 =
        *(const s16x8*)(qb + (size_t)(qbase + lane16) * DH + 32 + quad * 8);
#pragma unroll
    for (int i = 0; i < 8; i++) {
      qa0[i] = f2bft(bf2f(r0[i]) * c1);
      qa1[i] = f2bft(bf2f(r1[i]) * c1);
    }
  }
  STAGE_LOAD(0);
  STAGE_WRITE(0);
  __syncthreads();
  f32x4 O[4] = {};
  float lacc = 0.f;
  int rsw = ((lane16 & 7) << 4);      // read-side swizzle (rows = *16+lane16)
  int rc0 = (quad * 16) ^ rsw;        // swizzled byte col for first half
  int rc1 = (64 + quad * 16) ^ rsw;   // second half (dh 32..63 / keys 32..63)
  for (int kt = 0; kt <= qt; kt++) {
    int cur = kt & 1;
    if (kt < qt) STAGE_LOAD(kt + 1);  // issue early; hide behind compute
    bool diag = (kt == qt);
    // S^T = K * Q^T : per frag jk, rows = keys jk*16+quad*4+r, col = query
#pragma unroll
    for (int jk = 0; jk < 4; jk++) {
      s16x8 ka0 = *(const s16x8*)((const char*)&Ks[cur][jk * 16 + lane16][0] + rc0);
      s16x8 ka1 = *(const s16x8*)((const char*)&Ks[cur][jk * 16 + lane16][0] + rc1);
      f32x4 st = {};
      st = __builtin_amdgcn_mfma_f32_16x16x32_bf16(ka0, qa0, st, 0, 0, 0);
      st = __builtin_amdgcn_mfma_f32_16x16x32_bf16(ka1, qa1, st, 0, 0, 0);
      float4 ltv = *(const float4*)&Lts[cur][jk * 16 + quad * 4];
      float lt4[4] = {ltv.x, ltv.y, ltv.z, ltv.w};
      s16x4 pk;
#pragma unroll
      for (int r = 0; r < 4; r++) {
        float vv = fminf(st[r] + lt4[r], 126.f);
        float p = exp2f(vv);
        if (diag)
          p = (jk * 16 + quad * 4 + r <= wave * 16 + lane16) ? p : 0.f;
        lacc += p;
        pk[r] = f2bft(p);
      }
      *(s16x4*)&Pt[wave][lane16][jk * 16 + quad * 4] = pk;
    }
    // PV: O^T[dh][q] += V^T * P   (A = V^T frag, B = Pt frag)
    s16x8 pf0 = *(const s16x8*)&Pt[wave][lane16][quad * 8];
    s16x8 pf1 = *(const s16x8*)&Pt[wave][lane16][32 + quad * 8];
#pragma unroll
    for (int d = 0; d < 4; d++) {
      s16x8 av0 = *(const s16x8*)((const char*)&Vs[cur][d * 16 + lane16][0] + rc0);
      s16x8 av1 = *(const s16x8*)((const char*)&Vs[cur][d * 16 + lane16][0] + rc1);
      O[d] = __builtin_amdgcn_mfma_f32_16x16x32_bf16(av0, pf0, O[d], 0, 0, 0);
      O[d] = __builtin_amdgcn_mfma_f32_16x16x32_bf16(av1, pf1, O[d], 0, 0, 0);
    }
    if (kt < qt) STAGE_WRITE(cur ^ 1);
    __syncthreads();
  }
  // reduce l across the 4 quads (each quad summed a disjoint key subset)
  lacc += __shfl_xor(lacc, 16, 64);
  lacc += __shfl_xor(lacc, 32, 64);
  int qg = qbase + lane16;
  float scl = Th[(size_t)bh * S + qg] / lacc;
  unsigned short* op = ao + (size_t)(b * S + qg) * D + hh * DH;
#pragma unroll
  for (int d = 0; d < 4; d++) {
    s16x4 pk;
#pragma unroll
    for (int r = 0; r < 4; r++) pk[r] = f2bft(O[d][r] * scl);
    *(s16x4*)(op + d * 16 + quad * 4) = pk;
  }
#undef STAGE_LOAD
#undef STAGE_WRITE
}

extern "C" void kernel_launch(void* const* d_in, const int* in_sizes, int n_in,
                              void* d_out, int out_size, void* d_ws,
                              size_t ws_size, hipStream_t stream) {
  const float* x = (const float*)d_in[0];
  const float* phase = (const float*)d_in[1];
  const float* Wq = (const float*)d_in[2];
  const float* Wk = (const float*)d_in[3];
  const float* Wv = (const float*)d_in[4];
  const float* Wo = (const float*)d_in[5];
  const float* gamma = (const float*)d_in[6];
  const float* beta = (const float*)d_in[7];
  const float* exps = (const float*)d_in[8];
  const float* cph = (const float*)d_in[9];
  const float* bal = (const float*)d_in[10];
  float* out = (float*)d_out;

  unsigned short* hbuf = (unsigned short*)d_ws;        // MAT bf16
  float* Thbuf = (float*)(hbuf + MAT);                 // BH*S fp32
  float* Ltbuf = Thbuf + (size_t)BH * S;               // BH*S fp32
  unsigned short* qbuf = (unsigned short*)(Ltbuf + (size_t)BH * S);
  unsigned short* kbuf = qbuf + MAT;
  unsigned short* vtbuf = kbuf + MAT;                  // V^T bf16 (B,H,DH,S)
  unsigned short* aobuf = vtbuf + MAT;                 // attn out bf16 (B,S,D)
  unsigned short* wq_t = aobuf + MAT;                  // 4 x D*D bf16
  unsigned short* wk_t = wq_t + (size_t)D * D;
  unsigned short* wv_t = wk_t + (size_t)D * D;
  unsigned short* wo_t = wv_t + (size_t)D * D;

  hipLaunchKernelGGL(k_prep, dim3(8448), dim3(256), 0, stream, x, gamma, beta,
                     hbuf, phase, cph, bal, Thbuf, Ltbuf, Wq, Wk, Wv, Wo, wq_t,
                     wk_t, wv_t, wo_t);
  hipLaunchKernelGGL(k_gemm_qkvv, dim3(384), dim3(512), 0, stream, hbuf, wq_t,
                     wk_t, wv_t, exps, qbuf, kbuf, vtbuf);
  hipLaunchKernelGGL(k_attn_mfma, dim3(1024), dim3(256), 0, stream, qbuf,
                     kbuf, vtbuf, Thbuf, Ltbuf, bal, aobuf);
  hipLaunchKernelGGL(k_gemm_out_mfma, dim3(512), dim3(256), 0, stream, aobuf,
                     wo_t, x, out);
}

// Round 19
// 196.238 us; speedup vs baseline: 1.0815x; 1.0150x over previous
//
#include <hip/hip_runtime.h>
#include <math.h>

namespace {
constexpr int B = 2, S = 2048, D = 1024, H = 16, DH = 64;
constexpr int BH = B * H;               // 32
constexpr int BS = B * S;               // 4096
constexpr size_t MAT = (size_t)BS * D;  // 4194304 elems per (B,S,D) buffer
constexpr int QT = S / 64;              // 32 q-tiles
}

typedef __attribute__((ext_vector_type(8))) short s16x8;
typedef __attribute__((ext_vector_type(4))) short s16x4;
typedef __attribute__((ext_vector_type(4))) float f32x4;

__device__ inline unsigned short f2bf(float f) {
  union { float f; unsigned u; } c; c.f = f;
  unsigned r = c.u + 0x7fffu + ((c.u >> 16) & 1u);
  return (unsigned short)(r >> 16);
}
// fast round-half-up bf16 (fine for p >= 0)
__device__ inline short f2bft(float f) {
  union { float f; unsigned u; } c; c.f = f;
  return (short)((c.u + 0x8000u) >> 16);
}
__device__ inline float bf2f(short s) {
  union { unsigned u; float f; } c;
  c.u = ((unsigned)(unsigned short)s) << 16;
  return c.f;
}
// async global->LDS, 16 B per lane; LDS dest = wave-uniform base + lane*16.
// R9 lesson: lane->global mapping must be segment-identity; permuting lanes
// within the 128B segment defeats the DMA coalescer (61 -> 99 us).
__device__ inline void gld16(const unsigned short* g, unsigned short* l) {
  __builtin_amdgcn_global_load_lds(
      (const __attribute__((address_space(1))) unsigned int*)g,
      (__attribute__((address_space(3))) unsigned int*)l, 16, 0, 0);
}

// ---- Fused prep: convw (blocks 0..4095) | ln (4096..8191) | phase (8192..) ----
// R27: LN reductions via wave shfl_xor + 4 partials in LDS: 17 barriers -> 2.
__global__ __launch_bounds__(256) void k_prep(
    const float* __restrict__ x, const float* __restrict__ gamma,
    const float* __restrict__ beta, unsigned short* __restrict__ h,
    const float* __restrict__ phase, const float* __restrict__ cp,
    const float* __restrict__ bal, float* __restrict__ Th,
    float* __restrict__ Lt, const float* __restrict__ W0,
    const float* __restrict__ W1, const float* __restrict__ W2,
    const float* __restrict__ W3, unsigned short* __restrict__ T0,
    unsigned short* __restrict__ T1, unsigned short* __restrict__ T2,
    unsigned short* __restrict__ T3) {
  __shared__ float shbuf[32 * 33];
  int id = blockIdx.x;
  int t = threadIdx.x;
  if (id < 4096) {
    // ---- weight transpose + bf16 convert: Wt[n][k] ----
    int z = id & 3;
    int bx = ((id >> 2) & 31) * 32;  // n base
    int by = (id >> 7) * 32;         // k base
    const float* W = (z == 0) ? W0 : (z == 1) ? W1 : (z == 2) ? W2 : W3;
    unsigned short* T = (z == 0) ? T0 : (z == 1) ? T1 : (z == 2) ? T2 : T3;
    int tc = t & 31, tr = t >> 5;
    float(*tile)[33] = (float(*)[33])shbuf;
#pragma unroll
    for (int i = 0; i < 4; i++)
      tile[tr + 8 * i][tc] = W[(size_t)(by + tr + 8 * i) * D + bx + tc];
    __syncthreads();
#pragma unroll
    for (int i = 0; i < 4; i++)
      T[(size_t)(bx + tr + 8 * i) * D + by + tc] = f2bf(tile[tc][tr + 8 * i]);
  } else if (id < 8192) {
    // ---- LayerNorm row, bf16 out; wave-reduce (2 barriers total) ----
    int row = id - 4096;
    const float* xr = x + (size_t)row * D;
    int wv = t >> 6;
    float v[4];
    float s = 0.f;
#pragma unroll
    for (int i = 0; i < 4; i++) {
      v[i] = xr[t + 256 * i];
      s += v[i];
    }
#pragma unroll
    for (int off = 32; off > 0; off >>= 1) s += __shfl_xor(s, off, 64);
    if ((t & 63) == 0) shbuf[wv] = s;
    __syncthreads();
    float mu = (shbuf[0] + shbuf[1] + shbuf[2] + shbuf[3]) * (1.0f / D);
    float s2 = 0.f;
#pragma unroll
    for (int i = 0; i < 4; i++) {
      float d0 = v[i] - mu;
      s2 += d0 * d0;
    }
#pragma unroll
    for (int off = 32; off > 0; off >>= 1) s2 += __shfl_xor(s2, off, 64);
    if ((t & 63) == 0) shbuf[4 + wv] = s2;
    __syncthreads();
    float var = (shbuf[4] + shbuf[5] + shbuf[6] + shbuf[7]) * (1.0f / D);
    float r = rsqrtf(var + 1e-5f);
    unsigned short* hr = h + (size_t)row * D;
#pragma unroll
    for (int i = 0; i < 4; i++) {
      int c = t + 256 * i;
      hr[c] = f2bf((v[i] - mu) * r * gamma[c] + beta[c]);
    }
  } else {
    // ---- carrier resonance: Th and Lt = log2(T+1e-6)/tau ----
    int idx = (id - 8192) * 256 + t;  // over BH*S = 65536
    int s = idx & (S - 1);
    int bh = idx >> 11;
    int hh = bh & (H - 1);
    int b = bh >> 4;
    float tau = fminf(fmaxf(1.0f / (2.0f * bal[0] + 1e-8f), 0.1f), 10.0f);
    float c = cosf((phase[b * S + s] - cp[hh]) * 0.5f);
    float T = c * c;
    Th[idx] = T;
    Lt[idx] = __log2f(T + 1e-6f) * (1.0f / tau);
  }
}

// ------- Fused Q/K/V^T projection, R18: BM=256 x BN=128, 512 thr, 8 waves ---
// Measured R18: dropped out of top-5 (<50us, was 65us at 128^2).
__global__ __launch_bounds__(512) void k_gemm_qkvv(
    const unsigned short* __restrict__ hm, const unsigned short* __restrict__ Wq,
    const unsigned short* __restrict__ Wk, const unsigned short* __restrict__ Wv,
    const float* __restrict__ exps, unsigned short* __restrict__ q,
    unsigned short* __restrict__ kc, unsigned short* __restrict__ vt) {
  __shared__ __align__(16) unsigned short As[3][256][32];  // 48KB
  __shared__ __align__(16) unsigned short Bs[3][128][32];  // 24KB
  int id = blockIdx.x;
  int xcd = id & 7;
  int g = id >> 3;       // 0..47
  int z = g >> 4;        // 0=Q,1=K,2=V^T
  int w = g & 15;
  const unsigned short *Ap, *Bp;
  int tileM, tileN;
  if (z < 2) {
    Ap = hm; Bp = (z == 0) ? Wq : Wk;
    tileM = ((xcd >> 1) * 4 + (w >> 2)) * 256;  // seq: 16 tiles of 256
    tileN = ((xcd & 1) * 4 + (w & 3)) * 128;    // outdim: 8 tiles of 128
  } else {
    Ap = Wv; Bp = hm;
    tileM = ((xcd & 1) * 2 + (w >> 3)) * 256;   // outdim: 4 tiles of 256
    tileN = ((xcd >> 1) * 8 + (w & 7)) * 128;   // seq: 32 tiles of 128
  }
  int t = threadIdx.x;
  int wave = t >> 6, lane = t & 63, lane16 = lane & 15, quad = lane >> 4;
  int wm = (wave >> 1) * 64;   // 0..192 over BM=256
  int wn = (wave & 1) * 64;    // 0..64  over BN=128
  int chunkA = wave * 32;      // A rows this wave stages (2 gld16)
  int chunkB = wave * 16;      // B rows this wave stages (1 gld16)
  int srow = (lane >> 2), scol = (lane & 3) * 8;
  const unsigned short* aptr = Ap + (size_t)(tileM + chunkA + srow) * D + scol;
  const unsigned short* bptr = Bp + (size_t)(tileN + chunkB + srow) * D + scol;
  f32x4 acc[4][4] = {};
  // prologue: stage k-steps 0 and 1 (buffers 0,1); 6 loads in flight
  gld16(aptr, &As[0][chunkA][0]);
  gld16(aptr + (size_t)16 * D, &As[0][chunkA + 16][0]);
  gld16(bptr, &Bs[0][chunkB][0]);
  gld16(aptr + 32, &As[1][chunkA][0]);
  gld16(aptr + (size_t)16 * D + 32, &As[1][chunkA + 16][0]);
  gld16(bptr + 32, &Bs[1][chunkB][0]);
  int cur = 0;
  for (int k0 = 0; k0 < D; k0 += 32) {
    if (k0 + 32 < D)
      asm volatile("s_waitcnt vmcnt(3)" ::: "memory");
    else
      asm volatile("s_waitcnt vmcnt(0)" ::: "memory");
    asm volatile("s_barrier" ::: "memory");
    if (k0 + 64 < D) {
      int nxt = (cur >= 1) ? cur - 1 : 2;  // (cur+2)%3
      gld16(aptr + k0 + 64, &As[nxt][chunkA][0]);
      gld16(aptr + (size_t)16 * D + k0 + 64, &As[nxt][chunkA + 16][0]);
      gld16(bptr + k0 + 64, &Bs[nxt][chunkB][0]);
    }
    s16x8 af[4], bf[4];
#pragma unroll
    for (int i = 0; i < 4; i++) {
      af[i] = *(const s16x8*)&As[cur][wm + i * 16 + lane16][quad * 8];
      bf[i] = *(const s16x8*)&Bs[cur][wn + i * 16 + lane16][quad * 8];
    }
#pragma unroll
    for (int i = 0; i < 4; i++)
#pragma unroll
      for (int j = 0; j < 4; j++)
        acc[i][j] = __builtin_amdgcn_mfma_f32_16x16x32_bf16(af[i], bf[j],
                                                            acc[i][j], 0, 0, 0);
    cur = (cur == 2) ? 0 : cur + 1;
  }
  if (z < 2) {
    unsigned short* __restrict__ outp = (z == 0) ? q : kc;
    float e0 = exps[tileN >> 6];
    float e1 = exps[(tileN >> 6) + 1];
#pragma unroll
    for (int i = 0; i < 4; i++) {
#pragma unroll
      for (int r = 0; r < 4; r++) {
        int row = tileM + wm + i * 16 + quad * 4 + r;
        int b = row >> 11, s = row & (S - 1);
#pragma unroll
        for (int j = 0; j < 4; j++) {
          int cloc = wn + j * 16 + lane16;  // 0..127
          int head = (tileN + cloc) >> 6;
          int dh = cloc & 63;
          float val = acc[i][j][r];
          if (z != 0) {
            float e = (cloc >> 6) ? e1 : e0;
            float sgn = (val > 0.f) ? 1.f : ((val < 0.f) ? -1.f : 0.f);
            float mg = fmaxf(fabsf(val), 1e-8f);
            val = sgn * exp2f(e * __log2f(mg));
          }
          outp[((size_t)(b * H + head) * S + s) * DH + dh] = f2bf(val);
        }
      }
    }
  } else {
#pragma unroll
    for (int i = 0; i < 4; i++) {
#pragma unroll
      for (int r = 0; r < 4; r++) {
        int m = tileM + wm + i * 16 + quad * 4 + r;  // outdim
        int head = m >> 6, dh = m & 63;
        float e = exps[head];
#pragma unroll
        for (int j = 0; j < 4; j++) {
          int n = tileN + wn + j * 16 + lane16;  // seq
          int b = n >> 11, s = n & (S - 1);
          float val = acc[i][j][r];
          float sgn = (val > 0.f) ? 1.f : ((val < 0.f) ? -1.f : 0.f);
          float mg = fmaxf(fabsf(val), 1e-8f);
          val = sgn * exp2f(e * __log2f(mg));
          vt[((size_t)(b * H + head) * DH + dh) * S + s] = f2bf(val);
        }
      }
    }
  }
}

// ------ Output projection R26: 128x64 tiles, grid 512 = 2 blocks/CU ------
__global__ __launch_bounds__(256) void k_gemm_out_mfma(
    const unsigned short* __restrict__ am, const unsigned short* __restrict__ Wt,
    const float* __restrict__ x, float* __restrict__ outp) {
  __shared__ __align__(16) unsigned short As[3][128][32];  // 24KB
  __shared__ __align__(16) unsigned short Bs[3][64][32];   // 12KB
  int id = blockIdx.x;          // 0..511
  int xcd = id & 7;
  int inner = id >> 3;          // 0..63
  int tileM = ((xcd >> 1) * 8 + (inner >> 3)) * 128;  // 32 M-tiles
  int tileN = ((xcd & 1) * 8 + (inner & 7)) * 64;     // 16 N-tiles
  int t = threadIdx.x;
  int wave = t >> 6, lane = t & 63, lane16 = lane & 15, quad = lane >> 4;
  int wm = (wave >> 1) * 64;    // 0 or 64 over BM=128
  int wn = (wave & 1) * 32;     // 0 or 32 over BN=64
  int chunkA = wave * 32;       // A rows staged (2 gld16)
  int chunkB = wave * 16;       // B rows staged (1 gld16)
  int srow = (lane >> 2), scol = (lane & 3) * 8;
  const unsigned short* aptr = am + (size_t)(tileM + chunkA + srow) * D + scol;
  const unsigned short* bptr = Wt + (size_t)(tileN + chunkB + srow) * D + scol;
  f32x4 acc[4][2] = {};
  gld16(aptr, &As[0][chunkA][0]);
  gld16(aptr + (size_t)16 * D, &As[0][chunkA + 16][0]);
  gld16(bptr, &Bs[0][chunkB][0]);
  gld16(aptr + 32, &As[1][chunkA][0]);
  gld16(aptr + (size_t)16 * D + 32, &As[1][chunkA + 16][0]);
  gld16(bptr + 32, &Bs[1][chunkB][0]);
  int cur = 0;
  for (int k0 = 0; k0 < D; k0 += 32) {
    if (k0 + 32 < D)
      asm volatile("s_waitcnt vmcnt(3)" ::: "memory");
    else
      asm volatile("s_waitcnt vmcnt(0)" ::: "memory");
    asm volatile("s_barrier" ::: "memory");
    if (k0 + 64 < D) {
      int nxt = (cur >= 1) ? cur - 1 : 2;  // (cur+2)%3
      gld16(aptr + k0 + 64, &As[nxt][chunkA][0]);
      gld16(aptr + (size_t)16 * D + k0 + 64, &As[nxt][chunkA + 16][0]);
      gld16(bptr + k0 + 64, &Bs[nxt][chunkB][0]);
    }
    s16x8 af[4], bf[2];
#pragma unroll
    for (int i = 0; i < 4; i++)
      af[i] = *(const s16x8*)&As[cur][wm + i * 16 + lane16][quad * 8];
#pragma unroll
    for (int j = 0; j < 2; j++)
      bf[j] = *(const s16x8*)&Bs[cur][wn + j * 16 + lane16][quad * 8];
#pragma unroll
    for (int i = 0; i < 4; i++)
#pragma unroll
      for (int j = 0; j < 2; j++)
        acc[i][j] = __builtin_amdgcn_mfma_f32_16x16x32_bf16(af[i], bf[j],
                                                            acc[i][j], 0, 0, 0);
    cur = (cur == 2) ? 0 : cur + 1;
  }
#pragma unroll
  for (int i = 0; i < 4; i++) {
#pragma unroll
    for (int r = 0; r < 4; r++) {
      int row = tileM + wm + i * 16 + quad * 4 + r;
      const float* xr = x + (size_t)row * D;
      float* orow = outp + (size_t)row * D;
#pragma unroll
      for (int j = 0; j < 2; j++) {
        int col = tileN + wn + j * 16 + lane16;
        orow[col] = xr[col] + acc[i][j][r];
      }
    }
  }
}

// ------- MFMA flash attention R24 (verified 47.0us): swizzled Ks/Vs -------
__global__ __launch_bounds__(256) void k_attn_mfma(
    const unsigned short* __restrict__ q, const unsigned short* __restrict__ kc,
    const unsigned short* __restrict__ vt, const float* __restrict__ Th,
    const float* __restrict__ Lt, const float* __restrict__ bal,
    unsigned short* __restrict__ ao) {
  __shared__ __align__(16) unsigned short Ks[2][64][64];   // [buf][key][dh] swz
  __shared__ __align__(16) unsigned short Vs[2][64][64];   // [buf][dh][key] swz
  __shared__ __align__(16) unsigned short Pt[4][16][72];   // [wave][query][key]
  __shared__ __align__(16) float Lts[2][64];
  int id = blockIdx.x;
  int bh = (id & 7) + 8 * ((id >> 3) & 3);  // XCD-affine head mapping
  int qt = QT - 1 - (id >> 5);              // 31..0: long blocks first
  int t = threadIdx.x;
  int wave = t >> 6, lane = t & 63;
  int lane16 = lane & 15, quad = lane >> 4;
  float tau = fminf(fmaxf(1.0f / (2.0f * bal[0] + 1e-8f), 0.1f), 10.0f);
  float c1 = 0.125f * (1.0f / tau) * 1.44269504f;  // fold into Q
  const unsigned short* qb = q + (size_t)bh * S * DH;
  const unsigned short* kb = kc + (size_t)bh * S * DH;
  const unsigned short* vb = vt + (size_t)bh * DH * S;
  const float* Ltb = Lt + (size_t)bh * S;
  int b = bh >> 4, hh = bh & (H - 1);
  int cr = t >> 3, cc = (t & 7) * 8;  // staging coords
  int wsw = ((cr & 7) << 4);          // write-side swizzle (same for cr+32)
  int wcol = (cc * 2) ^ wsw;          // swizzled byte offset within row
  s16x8 nk0, nk1, nv0, nv1;
  float4 nlt;
#define STAGE_LOAD(KT)                                                  \
  do {                                                                  \
    nk0 = *(const s16x8*)(kb + (size_t)((KT) * 64 + cr) * DH + cc);     \
    nk1 = *(const s16x8*)(kb + (size_t)((KT) * 64 + cr + 32) * DH + cc);\
    nv0 = *(const s16x8*)(vb + (size_t)cr * S + (KT) * 64 + cc);        \
    nv1 = *(const s16x8*)(vb + (size_t)(cr + 32) * S + (KT) * 64 + cc); \
    if (t < 16) nlt = ((const float4*)(Ltb + (KT) * 64))[t];            \
  } while (0)
#define STAGE_WRITE(BF)                                                 \
  do {                                                                  \
    *(s16x8*)((char*)&Ks[BF][cr][0] + wcol) = nk0;                      \
    *(s16x8*)((char*)&Ks[BF][cr + 32][0] + wcol) = nk1;                 \
    *(s16x8*)((char*)&Vs[BF][cr][0] + wcol) = nv0;                      \
    *(s16x8*)((char*)&Vs[BF][cr + 32][0] + wcol) = nv1;                 \
    if (t < 16) ((float4*)Lts[BF])[t] = nlt;                            \
  } while (0)
  int qbase = qt * 64 + wave * 16;
  // Q as B-frag (B[k=quad*8+j][n=lane16]), pre-scaled by c1 in bf16
  s16x8 qa0, qa1;
  {
    s16x8 r0 = *(const s16x8*)(qb + (size_t)(qbase + lane16) * DH + quad * 8);
    s16x8 r1 =
        *(const s16x8*)(qb + (size_t)(qbase + lane16) * DH + 32 + quad * 8);
#pragma unroll
    for (int i = 0; i < 8; i++) {
      qa0[i] = f2bft(bf2f(r0[i]) * c1);
      qa1[i] = f2bft(bf2f(r1[i]) * c1);
    }
  }
  STAGE_LOAD(0);
  STAGE_WRITE(0);
  __syncthreads();
  f32x4 O[4] = {};
  float lacc = 0.f;
  int rsw = ((lane16 & 7) << 4);      // read-side swizzle (rows = *16+lane16)
  int rc0 = (quad * 16) ^ rsw;        // swizzled byte col for first half
  int rc1 = (64 + quad * 16) ^ rsw;   // second half (dh 32..63 / keys 32..63)
  for (int kt = 0; kt <= qt; kt++) {
    int cur = kt & 1;
    if (kt < qt) STAGE_LOAD(kt + 1);  // issue early; hide behind compute
    bool diag = (kt == qt);
    // S^T = K * Q^T : per frag jk, rows = keys jk*16+quad*4+r, col = query
#pragma unroll
    for (int jk = 0; jk < 4; jk++) {
      s16x8 ka0 = *(const s16x8*)((const char*)&Ks[cur][jk * 16 + lane16][0] + rc0);
      s16x8 ka1 = *(const s16x8*)((const char*)&Ks[cur][jk * 16 + lane16][0] + rc1);
      f32x4 st = {};
      st = __builtin_amdgcn_mfma_f32_16x16x32_bf16(ka0, qa0, st, 0, 0, 0);
      st = __builtin_amdgcn_mfma_f32_16x16x32_bf16(ka1, qa1, st, 0, 0, 0);
      float4 ltv = *(const float4*)&Lts[cur][jk * 16 + quad * 4];
      float lt4[4] = {ltv.x, ltv.y, ltv.z, ltv.w};
      s16x4 pk;
#pragma unroll
      for (int r = 0; r < 4; r++) {
        float vv = fminf(st[r] + lt4[r], 126.f);
        float p = exp2f(vv);
        if (diag)
          p = (jk * 16 + quad * 4 + r <= wave * 16 + lane16) ? p : 0.f;
        lacc += p;
        pk[r] = f2bft(p);
      }
      *(s16x4*)&Pt[wave][lane16][jk * 16 + quad * 4] = pk;
    }
    // PV: O^T[dh][q] += V^T * P   (A = V^T frag, B = Pt frag)
    s16x8 pf0 = *(const s16x8*)&Pt[wave][lane16][quad * 8];
    s16x8 pf1 = *(const s16x8*)&Pt[wave][lane16][32 + quad * 8];
#pragma unroll
    for (int d = 0; d < 4; d++) {
      s16x8 av0 = *(const s16x8*)((const char*)&Vs[cur][d * 16 + lane16][0] + rc0);
      s16x8 av1 = *(const s16x8*)((const char*)&Vs[cur][d * 16 + lane16][0] + rc1);
      O[d] = __builtin_amdgcn_mfma_f32_16x16x32_bf16(av0, pf0, O[d], 0, 0, 0);
      O[d] = __builtin_amdgcn_mfma_f32_16x16x32_bf16(av1, pf1, O[d], 0, 0, 0);
    }
    if (kt < qt) STAGE_WRITE(cur ^ 1);
    __syncthreads();
  }
  // reduce l across the 4 quads (each quad summed a disjoint key subset)
  lacc += __shfl_xor(lacc, 16, 64);
  lacc += __shfl_xor(lacc, 32, 64);
  int qg = qbase + lane16;
  float scl = Th[(size_t)bh * S + qg] / lacc;
  unsigned short* op = ao + (size_t)(b * S + qg) * D + hh * DH;
#pragma unroll
  for (int d = 0; d < 4; d++) {
    s16x4 pk;
#pragma unroll
    for (int r = 0; r < 4; r++) pk[r] = f2bft(O[d][r] * scl);
    *(s16x4*)(op + d * 16 + quad * 4) = pk;
  }
#undef STAGE_LOAD
#undef STAGE_WRITE
}

extern "C" void kernel_launch(void* const* d_in, const int* in_sizes, int n_in,
                              void* d_out, int out_size, void* d_ws,
                              size_t ws_size, hipStream_t stream) {
  const float* x = (const float*)d_in[0];
  const float* phase = (const float*)d_in[1];
  const float* Wq = (const float*)d_in[2];
  const float* Wk = (const float*)d_in[3];
  const float* Wv = (const float*)d_in[4];
  const float* Wo = (const float*)d_in[5];
  const float* gamma = (const float*)d_in[6];
  const float* beta = (const float*)d_in[7];
  const float* exps = (const float*)d_in[8];
  const float* cph = (const float*)d_in[9];
  const float* bal = (const float*)d_in[10];
  float* out = (float*)d_out;

  unsigned short* hbuf = (unsigned short*)d_ws;        // MAT bf16
  float* Thbuf = (float*)(hbuf + MAT);                 // BH*S fp32
  float* Ltbuf = Thbuf + (size_t)BH * S;               // BH*S fp32
  unsigned short* qbuf = (unsigned short*)(Ltbuf + (size_t)BH * S);
  unsigned short* kbuf = qbuf + MAT;
  unsigned short* vtbuf = kbuf + MAT;                  // V^T bf16 (B,H,DH,S)
  unsigned short* aobuf = vtbuf + MAT;                 // attn out bf16 (B,S,D)
  unsigned short* wq_t = aobuf + MAT;                  // 4 x D*D bf16
  unsigned short* wk_t = wq_t + (size_t)D * D;
  unsigned short* wv_t = wk_t + (size_t)D * D;
  unsigned short* wo_t = wv_t + (size_t)D * D;

  hipLaunchKernelGGL(k_prep, dim3(8448), dim3(256), 0, stream, x, gamma, beta,
                     hbuf, phase, cph, bal, Thbuf, Ltbuf, Wq, Wk, Wv, Wo, wq_t,
                     wk_t, wv_t, wo_t);
  hipLaunchKernelGGL(k_gemm_qkvv, dim3(384), dim3(512), 0, stream, hbuf, wq_t,
                     wk_t, wv_t, exps, qbuf, kbuf, vtbuf);
  hipLaunchKernelGGL(k_attn_mfma, dim3(1024), dim3(256), 0, stream, qbuf,
                     kbuf, vtbuf, Thbuf, Ltbuf, bal, aobuf);
  hipLaunchKernelGGL(k_gemm_out_mfma, dim3(512), dim3(256), 0, stream, aobuf,
                     wo_t, x, out);
}